// Round 9
// baseline (208.295 us; speedup 1.0000x reference)
//
#include <hip/hip_runtime.h>
#include <hip/hip_bf16.h>

#define B_ROWS 32768
#define L_DIM 512
#define H_DIM 1024
#define E_DIM 128
#define K_EXP 8
#define NBLK 128          // sort blocks: 32768/256
#define MAXT 264          // max padded 128-row tiles (256 + 8)
#define MAXB (MAXT * 128) // 33792

typedef __bf16 bf16x8 __attribute__((ext_vector_type(8)));
typedef float f32x4 __attribute__((ext_vector_type(4)));

__device__ __forceinline__ void gload16(const void* src, void* dst) {
    __builtin_amdgcn_global_load_lds(
        (const __attribute__((address_space(1))) unsigned int*)src,
        (__attribute__((address_space(3))) unsigned int*)dst, 16, 0, 0);
}

// meta: [0]=nT [1..9]=seg [10..18]=segP [19..26]=cnt [27..27+MAXT)=texp
#define M_NT 0
#define M_SEG 1
#define M_SEGP 10
#define M_CNT 19
#define M_TEXP 27

// ---------------- sort: ids + per-block histogram ----------------
__global__ void k_ids_hist(const float* __restrict__ x, int* __restrict__ ids,
                           int* __restrict__ hist) {
    __shared__ int lh[K_EXP];
    int t = threadIdx.x;
    if (t < K_EXP) lh[t] = 0;
    __syncthreads();
    int i = blockIdx.x * 256 + t;
    int id = (int)x[(size_t)i * (L_DIM + 1) + L_DIM];
    ids[i] = id;
    atomicAdd(&lh[id], 1);
    __syncthreads();
    if (t < K_EXP) hist[blockIdx.x * K_EXP + t] = lh[t];
}

// ---------------- scan: 128-padded segments, tile->expert map (R6-proven) ----------------
__global__ void k_scan(const int* __restrict__ hist, int* __restrict__ base,
                       int* __restrict__ meta, int* __restrict__ order_pad) {
    __shared__ int c[K_EXP];
    __shared__ int sp[K_EXP + 1];
    __shared__ int scnt[K_EXP];
    int k = threadIdx.x;  // 64 threads
    if (k < K_EXP) {
        int run = 0;
        for (int b = 0; b < NBLK; ++b) {
            base[b * K_EXP + k] = run;
            run += hist[b * K_EXP + k];
        }
        c[k] = run;
    }
    __syncthreads();
    if (k == 0) {
        int s = 0, p = 0;
        for (int e = 0; e < K_EXP; ++e) {
            meta[M_SEG + e] = s;
            meta[M_SEGP + e] = p;
            meta[M_CNT + e] = c[e];
            sp[e] = p;
            scnt[e] = c[e];
            s += c[e];
            p += ((c[e] + 127) >> 7) << 7;
        }
        meta[M_SEG + K_EXP] = s;
        meta[M_SEGP + K_EXP] = p;
        sp[K_EXP] = p;
        int nT = p >> 7;
        meta[M_NT] = nT;
        for (int e = 0; e < K_EXP; ++e)
            for (int t2 = sp[e] >> 7; t2 < sp[e + 1] >> 7; ++t2)
                meta[M_TEXP + t2] = e;
        for (int t2 = nT; t2 < MAXT; ++t2) meta[M_TEXP + t2] = 0;
    }
    __syncthreads();
    if (k < K_EXP) {
        int s0 = sp[k];
        for (int b = 0; b < NBLK; ++b) base[b * K_EXP + k] += s0;
    }
    for (int e = 0; e < K_EXP; ++e) {
        int st = sp[e] + scnt[e], en = sp[e + 1];
        for (int p2 = st + k; p2 < en; p2 += 64) order_pad[p2] = 0;
    }
    for (int p2 = sp[K_EXP] + k; p2 < MAXB; p2 += 64) order_pad[p2] = 0;
}

// ---------------- stable order within block ----------------
__global__ void k_order(const int* __restrict__ ids, const int* __restrict__ base,
                        int* __restrict__ order) {
    __shared__ int sid[256];
    int t = threadIdx.x;
    int i = blockIdx.x * 256 + t;
    int my = ids[i];
    sid[t] = my;
    __syncthreads();
    int rank = 0;
    for (int j = 0; j < t; ++j) rank += (sid[j] == my) ? 1 : 0;
    order[base[blockIdx.x * K_EXP + my] + rank] = i;
}

// ---------------- gather sorted (padded) rows into packed bf16 xs ----------------
__global__ void k_gather(const float* __restrict__ x, const int* __restrict__ order,
                         __hip_bfloat16* __restrict__ xs) {
    int idx = blockIdx.x * 256 + threadIdx.x;
    int p = idx >> 7;
    int c4 = (idx & 127) << 2;
    int src = order[p];
    const float* sp = x + (size_t)src * (L_DIM + 1) + c4;
    __hip_bfloat16 v[4];
    v[0] = __float2bfloat16(sp[0]);
    v[1] = __float2bfloat16(sp[1]);
    v[2] = __float2bfloat16(sp[2]);
    v[3] = __float2bfloat16(sp[3]);
    *(uint2*)(xs + (size_t)p * L_DIM + c4) = *(uint2*)v;
}

// ---------------- fused weight transpose + fp32->bf16 (1 launch, R8-proven) ----------------
__global__ void k_wtrans(const float* __restrict__ We1, const float* __restrict__ We2,
                         const float* __restrict__ Wd1, const float* __restrict__ Wd2,
                         __hip_bfloat16* __restrict__ Wt1, __hip_bfloat16* __restrict__ Wt2,
                         __hip_bfloat16* __restrict__ Wd1t, __hip_bfloat16* __restrict__ Wd2t) {
    __shared__ float tile[32][33];
    int b = blockIdx.x;
    const float* W;
    __hip_bfloat16* Wt;
    int KDim, NDim, local;
    if (b < 512)       { W = We1; Wt = Wt1; KDim = 512;  NDim = 1024; local = b; }
    else if (b < 640)  { W = We2; Wt = Wt2; KDim = 1024; NDim = 128;  local = b - 512; }
    else if (b < 1664) {
        int lb = b - 640;
        int e = lb >> 7;
        local = lb & 127;
        KDim = 128; NDim = 1024;
        W = Wd1 + (size_t)e * KDim * NDim;
        Wt = Wd1t + (size_t)e * KDim * NDim;
    } else {
        int lb = b - 1664;
        int e = lb >> 9;
        local = lb & 511;
        KDim = 1024; NDim = 512;
        W = Wd2 + (size_t)e * KDim * NDim;
        Wt = Wd2t + (size_t)e * KDim * NDim;
    }
    int ntK = KDim >> 5;
    int k0 = (local % ntK) << 5, n0 = (local / ntK) << 5;
    int tx = threadIdx.x & 31, ty = threadIdx.x >> 5;
    for (int i = ty; i < 32; i += 8)
        tile[i][tx] = W[(size_t)(k0 + i) * NDim + n0 + tx];
    __syncthreads();
    for (int i = ty; i < 32; i += 8)
        Wt[(size_t)(n0 + i) * KDim + k0 + tx] = __float2bfloat16(tile[tx][i]);
}

// ---------------- G1: dense 128x128 ring-3 (R5/R8-proven body) ----------------
__global__ __launch_bounds__(256) void gemm_g1(const __hip_bfloat16* __restrict__ A,
                                               const __hip_bfloat16* __restrict__ Bt,
                                               const float* __restrict__ bias,
                                               __hip_bfloat16* __restrict__ Cout) {
    constexpr int KD = L_DIM, ND = H_DIM;
    constexpr int NNT = ND / 128;          // 8
    constexpr int TOT = MAXT * NNT;        // 2112
    constexpr int SLOT = 2 * 128 * 32;
    constexpr int NK = KD / 32;
    __shared__ __align__(16) __hip_bfloat16 smem[3 * SLOT];  // 48 KB
    const int id = blockIdx.x;
    const int wg = (id & 7) * (TOT / 8) + (id >> 3);
    const int mt = wg / NNT, nt = wg % NNT;
    const int m0 = mt << 7, n0 = nt << 7;
    const int t = threadIdx.x, w = t >> 6, l = t & 63;
    const int wm = w >> 1, wn = w & 1, g = l >> 4, li = l & 15;
    const int q0 = 2 * w, r0 = l >> 2, s0 = l & 3;

    f32x4 acc[4][4];
#pragma unroll
    for (int i = 0; i < 4; ++i)
#pragma unroll
        for (int j = 0; j < 4; ++j) acc[i][j] = (f32x4){0.f, 0.f, 0.f, 0.f};

    auto stage = [&](int b, int kt) {
#pragma unroll
        for (int qi = 0; qi < 2; ++qi) {
            int q = q0 + qi, r = q * 16 + r0;
            int ksg = s0 ^ ((r >> 1) & 3);
            gload16(A + (size_t)(m0 + r) * KD + kt * 32 + ksg * 8,
                    &smem[b * SLOT + q * 512]);
        }
#pragma unroll
        for (int qi = 0; qi < 2; ++qi) {
            int q = q0 + qi, r = q * 16 + r0;
            int ksg = s0 ^ ((r >> 1) & 3);
            gload16(Bt + (size_t)(n0 + r) * KD + kt * 32 + ksg * 8,
                    &smem[b * SLOT + 4096 + q * 512]);
        }
    };

    stage(0, 0);
    stage(1, 1);
    int b = 0;
    for (int kt = 0; kt < NK; ++kt) {
        if (kt == NK - 1)
            asm volatile("s_waitcnt vmcnt(0)\ns_barrier" ::: "memory");
        else
            asm volatile("s_waitcnt vmcnt(4)\ns_barrier" ::: "memory");
        __builtin_amdgcn_sched_barrier(0);
        if (kt + 2 < NK) stage((b + 2 >= 3) ? b - 1 : b + 2, kt + 2);
        bf16x8 af[4], bfr[4];
#pragma unroll
        for (int fm = 0; fm < 4; ++fm) {
            int rr = wm * 64 + fm * 16 + li;
            int ss = g ^ ((rr >> 1) & 3);
            af[fm] = *(const bf16x8*)&smem[b * SLOT + rr * 32 + ss * 8];
        }
#pragma unroll
        for (int fn = 0; fn < 4; ++fn) {
            int cc = wn * 64 + fn * 16 + li;
            int ss = g ^ ((cc >> 1) & 3);
            bfr[fn] = *(const bf16x8*)&smem[b * SLOT + 4096 + cc * 32 + ss * 8];
        }
        __builtin_amdgcn_s_setprio(1);
#pragma unroll
        for (int fm = 0; fm < 4; ++fm)
#pragma unroll
            for (int fn = 0; fn < 4; ++fn)
                acc[fm][fn] = __builtin_amdgcn_mfma_f32_16x16x32_bf16(
                    af[fm], bfr[fn], acc[fm][fn], 0, 0, 0);
        __builtin_amdgcn_s_setprio(0);
        b = (b + 1 >= 3) ? 0 : b + 1;
    }

    float bv[4];
#pragma unroll
    for (int fn = 0; fn < 4; ++fn) bv[fn] = bias[n0 + wn * 64 + fn * 16 + li];
#pragma unroll
    for (int fm = 0; fm < 4; ++fm)
#pragma unroll
        for (int i = 0; i < 4; ++i) {
            int r = m0 + wm * 64 + fm * 16 + g * 4 + i;
#pragma unroll
            for (int fn = 0; fn < 4; ++fn) {
                float v = acc[fm][fn][i] + bv[fn];
                v = v > 0.f ? v : 0.01f * v;
                Cout[(size_t)r * ND + n0 + wn * 64 + fn * 16 + li] = __float2bfloat16(v);
            }
        }
}

// ---------------- G23: fused z=leaky(h@We2+be2) -> hd=leaky(z@Wd1[e]+bd1[e]) ----------------
// 64-row tiles (528 blocks, 2+/CU). Phase A: ring-3 K=1024 -> z in LDS (swizzled,
// R3-proven pattern). Phase B: 8 H-chunks x K=128 with A from LDS, B ring-streamed.
// hd written in-place over h (block reads its h rows fully before writing them).
__global__ __launch_bounds__(256) void gemm_g23(const __hip_bfloat16* __restrict__ h,
                                                const __hip_bfloat16* __restrict__ Wt2,
                                                const float* __restrict__ be2,
                                                const __hip_bfloat16* __restrict__ Wd1t,
                                                const float* __restrict__ bd1,
                                                __hip_bfloat16* __restrict__ hd,
                                                const int* __restrict__ meta) {
    constexpr int SLOTA = 64 * 32 + 128 * 32;  // 6144 elems (12 KB)
    constexpr int SLOTB = 128 * 32;            // 4096 elems (8 KB)
    constexpr int NKA = H_DIM / 32;            // 32
    __shared__ __align__(16) __hip_bfloat16 smem[3 * SLOTA + 64 * 128];  // 52 KB
    __hip_bfloat16* zl = smem + 3 * SLOTA;     // 64x128 swizzled z

    const int id = blockIdx.x;                 // 528 blocks
    const int wg = (id & 7) * 66 + (id >> 3);  // bijective XCD chunking (528/8=66)
    const int m0 = wg << 6;
    const int e = meta[M_TEXP + (wg >> 1)];
    const int t = threadIdx.x, w = t >> 6, l = t & 63;
    const int wm = w >> 1, wn = w & 1, g = l >> 4, li = l & 15;
    const int r0 = l >> 2, s0 = l & 3;

    // ---- phase A: z_tile[64x128] = leaky(h[m0..][1024] @ Wt2^T + be2) ----
    f32x4 accA[2][4];
#pragma unroll
    for (int i = 0; i < 2; ++i)
#pragma unroll
        for (int j = 0; j < 4; ++j) accA[i][j] = (f32x4){0.f, 0.f, 0.f, 0.f};

    auto stageA = [&](int b, int kt) {
        {
            int q = w, r = q * 16 + r0;
            int ksg = s0 ^ ((r >> 1) & 3);
            gload16(h + (size_t)(m0 + r) * H_DIM + kt * 32 + ksg * 8,
                    &smem[b * SLOTA + q * 512]);
        }
#pragma unroll
        for (int qi = 0; qi < 2; ++qi) {
            int q = 2 * w + qi, r = q * 16 + r0;
            int ksg = s0 ^ ((r >> 1) & 3);
            gload16(Wt2 + (size_t)r * H_DIM + kt * 32 + ksg * 8,
                    &smem[b * SLOTA + 2048 + q * 512]);
        }
    };

    stageA(0, 0);
    stageA(1, 1);
    int b = 0;
    for (int kt = 0; kt < NKA; ++kt) {
        if (kt == NKA - 1)
            asm volatile("s_waitcnt vmcnt(0)\ns_barrier" ::: "memory");
        else
            asm volatile("s_waitcnt vmcnt(3)\ns_barrier" ::: "memory");
        __builtin_amdgcn_sched_barrier(0);
        if (kt + 2 < NKA) stageA((b + 2 >= 3) ? b - 1 : b + 2, kt + 2);
        bf16x8 af[2], bfr[4];
#pragma unroll
        for (int fm = 0; fm < 2; ++fm) {
            int rr = wm * 32 + fm * 16 + li;
            int ss = g ^ ((rr >> 1) & 3);
            af[fm] = *(const bf16x8*)&smem[b * SLOTA + rr * 32 + ss * 8];
        }
#pragma unroll
        for (int fn = 0; fn < 4; ++fn) {
            int cc = wn * 64 + fn * 16 + li;
            int ss = g ^ ((cc >> 1) & 3);
            bfr[fn] = *(const bf16x8*)&smem[b * SLOTA + 2048 + cc * 32 + ss * 8];
        }
        __builtin_amdgcn_s_setprio(1);
#pragma unroll
        for (int fm = 0; fm < 2; ++fm)
#pragma unroll
            for (int fn = 0; fn < 4; ++fn)
                accA[fm][fn] = __builtin_amdgcn_mfma_f32_16x16x32_bf16(
                    af[fm], bfr[fn], accA[fm][fn], 0, 0, 0);
        __builtin_amdgcn_s_setprio(0);
        b = (b + 1 >= 3) ? 0 : b + 1;
    }

    // z -> LDS (bias+leaky+bf16, swizzled for phase-B A-fragments; R3-proven pattern)
#pragma unroll
    for (int fm = 0; fm < 2; ++fm)
#pragma unroll
        for (int i = 0; i < 4; ++i) {
            int r = wm * 32 + fm * 16 + g * 4 + i;
            int swr = (r >> 1) & 3;
#pragma unroll
            for (int fn = 0; fn < 4; ++fn) {
                int c = wn * 64 + fn * 16 + li;
                float v = accA[fm][fn][i] + be2[c];
                v = v > 0.f ? v : 0.01f * v;
                int kt = c >> 5, k32 = c & 31;
                zl[kt * 2048 + r * 32 + (((k32 >> 3) ^ swr) << 3) + (k32 & 7)] =
                    __float2bfloat16(v);
            }
        }
    __syncthreads();

    // ---- phase B: hd[64x1024] = leaky(z_lds @ Wd1t[e]^T + bd1[e]), 8 chunks ----
    const __hip_bfloat16* Bp = Wd1t + (size_t)e * H_DIM * E_DIM;
    const float* bp = bd1 + (size_t)e * H_DIM;

    auto stageB = [&](int bb, int step) {
        int chunk = step >> 2, kt = step & 3;
#pragma unroll
        for (int qi = 0; qi < 2; ++qi) {
            int q = 2 * w + qi, r = q * 16 + r0;
            int ksg = s0 ^ ((r >> 1) & 3);
            gload16(Bp + (size_t)(chunk * 128 + r) * E_DIM + kt * 32 + ksg * 8,
                    &smem[bb * SLOTB + q * 512]);
        }
    };

    f32x4 accB[2][4];
#pragma unroll
    for (int i = 0; i < 2; ++i)
#pragma unroll
        for (int j = 0; j < 4; ++j) accB[i][j] = (f32x4){0.f, 0.f, 0.f, 0.f};

    stageB(0, 0);
    stageB(1, 1);
    b = 0;
    for (int step = 0; step < 32; ++step) {
        int chunk = step >> 2, kt = step & 3;
        if (step == 31)
            asm volatile("s_waitcnt vmcnt(0)\ns_barrier" ::: "memory");
        else
            asm volatile("s_waitcnt vmcnt(2)\ns_barrier" ::: "memory");
        __builtin_amdgcn_sched_barrier(0);
        if (step + 2 < 32) stageB((b + 2 >= 3) ? b - 1 : b + 2, step + 2);
        bf16x8 af[2], bfr[4];
#pragma unroll
        for (int fm = 0; fm < 2; ++fm) {
            int rr = wm * 32 + fm * 16 + li;
            int ss = g ^ ((rr >> 1) & 3);
            af[fm] = *(const bf16x8*)&zl[kt * 2048 + rr * 32 + ss * 8];
        }
#pragma unroll
        for (int fn = 0; fn < 4; ++fn) {
            int cc = wn * 64 + fn * 16 + li;
            int ss = g ^ ((cc >> 1) & 3);
            bfr[fn] = *(const bf16x8*)&smem[b * SLOTB + cc * 32 + ss * 8];
        }
        __builtin_amdgcn_s_setprio(1);
#pragma unroll
        for (int fm = 0; fm < 2; ++fm)
#pragma unroll
            for (int fn = 0; fn < 4; ++fn)
                accB[fm][fn] = __builtin_amdgcn_mfma_f32_16x16x32_bf16(
                    af[fm], bfr[fn], accB[fm][fn], 0, 0, 0);
        __builtin_amdgcn_s_setprio(0);
        if (kt == 3) {
            // chunk epilogue: bias+leaky -> hd (in-place over h)
#pragma unroll
            for (int fm = 0; fm < 2; ++fm)
#pragma unroll
                for (int i = 0; i < 4; ++i) {
                    int r = m0 + wm * 32 + fm * 16 + g * 4 + i;
#pragma unroll
                    for (int fn = 0; fn < 4; ++fn) {
                        int c = chunk * 128 + wn * 64 + fn * 16 + li;
                        float v = accB[fm][fn][i] + bp[c];
                        v = v > 0.f ? v : 0.01f * v;
                        hd[(size_t)r * H_DIM + c] = __float2bfloat16(v);
                        accB[fm][fn][i] = 0.f;
                    }
                }
        }
        b = (b + 1 >= 3) ? 0 : b + 1;
    }
}

// ---------------- G4: grouped 128x128 ring-3, padded tiles, row-map epilogue ----------------
__global__ __launch_bounds__(256) void gemm_g4(const __hip_bfloat16* __restrict__ A,
                                               const __hip_bfloat16* __restrict__ Bt,
                                               const float* __restrict__ bias,
                                               float* __restrict__ Cout,
                                               const int* __restrict__ meta) {
    constexpr int KD = H_DIM, ND = L_DIM;
    constexpr int NNT = ND / 128;          // 4
    constexpr int TOT = MAXT * NNT;        // 1056
    constexpr int SLOT = 2 * 128 * 32;
    constexpr int NK = KD / 32;
    __shared__ __align__(16) __hip_bfloat16 smem[3 * SLOT];  // 48 KB
    const int id = blockIdx.x;
    const int wg = (id & 7) * (TOT / 8) + (id >> 3);
    const int mt = wg / NNT, nt = wg % NNT;
    const int e = meta[M_TEXP + mt];
    const int m0 = mt << 7, n0 = nt << 7;
    const __hip_bfloat16* Bp = Bt + (size_t)e * KD * ND;
    const float* bp = bias + (size_t)e * ND;
    const int t = threadIdx.x, w = t >> 6, l = t & 63;
    const int wm = w >> 1, wn = w & 1, g = l >> 4, li = l & 15;
    const int q0 = 2 * w, r0 = l >> 2, s0 = l & 3;

    f32x4 acc[4][4];
#pragma unroll
    for (int i = 0; i < 4; ++i)
#pragma unroll
        for (int j = 0; j < 4; ++j) acc[i][j] = (f32x4){0.f, 0.f, 0.f, 0.f};

    auto stage = [&](int b, int kt) {
#pragma unroll
        for (int qi = 0; qi < 2; ++qi) {
            int q = q0 + qi, r = q * 16 + r0;
            int ksg = s0 ^ ((r >> 1) & 3);
            gload16(A + (size_t)(m0 + r) * KD + kt * 32 + ksg * 8,
                    &smem[b * SLOT + q * 512]);
        }
#pragma unroll
        for (int qi = 0; qi < 2; ++qi) {
            int q = q0 + qi, r = q * 16 + r0;
            int ksg = s0 ^ ((r >> 1) & 3);
            gload16(Bp + (size_t)(n0 + r) * KD + kt * 32 + ksg * 8,
                    &smem[b * SLOT + 4096 + q * 512]);
        }
    };

    stage(0, 0);
    stage(1, 1);
    int b = 0;
    for (int kt = 0; kt < NK; ++kt) {
        if (kt == NK - 1)
            asm volatile("s_waitcnt vmcnt(0)\ns_barrier" ::: "memory");
        else
            asm volatile("s_waitcnt vmcnt(4)\ns_barrier" ::: "memory");
        __builtin_amdgcn_sched_barrier(0);
        if (kt + 2 < NK) stage((b + 2 >= 3) ? b - 1 : b + 2, kt + 2);
        bf16x8 af[4], bfr[4];
#pragma unroll
        for (int fm = 0; fm < 4; ++fm) {
            int rr = wm * 64 + fm * 16 + li;
            int ss = g ^ ((rr >> 1) & 3);
            af[fm] = *(const bf16x8*)&smem[b * SLOT + rr * 32 + ss * 8];
        }
#pragma unroll
        for (int fn = 0; fn < 4; ++fn) {
            int cc = wn * 64 + fn * 16 + li;
            int ss = g ^ ((cc >> 1) & 3);
            bfr[fn] = *(const bf16x8*)&smem[b * SLOT + 4096 + cc * 32 + ss * 8];
        }
        __builtin_amdgcn_s_setprio(1);
#pragma unroll
        for (int fm = 0; fm < 4; ++fm)
#pragma unroll
            for (int fn = 0; fn < 4; ++fn)
                acc[fm][fn] = __builtin_amdgcn_mfma_f32_16x16x32_bf16(
                    af[fm], bfr[fn], acc[fm][fn], 0, 0, 0);
        __builtin_amdgcn_s_setprio(0);
        b = (b + 1 >= 3) ? 0 : b + 1;
    }

    float bv[4];
#pragma unroll
    for (int fn = 0; fn < 4; ++fn) bv[fn] = bp[n0 + wn * 64 + fn * 16 + li];
    const int se = meta[M_SEG + e], sp2 = meta[M_SEGP + e], ce = meta[M_CNT + e];
#pragma unroll
    for (int fm = 0; fm < 4; ++fm)
#pragma unroll
        for (int i = 0; i < 4; ++i) {
            int rp = m0 + wm * 64 + fm * 16 + g * 4 + i;
            int local = rp - sp2;
            if (local < ce) {
#pragma unroll
                for (int fn = 0; fn < 4; ++fn) {
                    float v = acc[fm][fn][i] + bv[fn];
                    Cout[(size_t)(se + local) * ND + n0 + wn * 64 + fn * 16 + li] = v;
                }
            }
        }
}

extern "C" void kernel_launch(void* const* d_in, const int* in_sizes, int n_in,
                              void* d_out, int out_size, void* d_ws, size_t ws_size,
                              hipStream_t stream) {
    (void)in_sizes; (void)n_in; (void)out_size; (void)ws_size;
    const float* x   = (const float*)d_in[0];
    const float* We1 = (const float*)d_in[1];
    const float* be1 = (const float*)d_in[2];
    const float* We2 = (const float*)d_in[3];
    const float* be2 = (const float*)d_in[4];
    const float* Wd1 = (const float*)d_in[5];
    const float* bd1 = (const float*)d_in[6];
    const float* Wd2 = (const float*)d_in[7];
    const float* bd2 = (const float*)d_in[8];
    float* out = (float*)d_out;

    char* w = (char*)d_ws;
    auto alloc = [&](size_t bytes) {
        char* p = w;
        w += (bytes + 255) & ~(size_t)255;
        return p;
    };
    int* ids       = (int*)alloc((size_t)B_ROWS * 4);
    int* order_pad = (int*)alloc((size_t)MAXB * 4);
    int* hist      = (int*)alloc((size_t)NBLK * K_EXP * 4);
    int* base      = (int*)alloc((size_t)NBLK * K_EXP * 4);
    int* meta      = (int*)alloc((size_t)(M_TEXP + MAXT) * 4);
    __hip_bfloat16* xs   = (__hip_bfloat16*)alloc((size_t)MAXB * L_DIM * 2);   // 34.6 MB
    __hip_bfloat16* hbuf = (__hip_bfloat16*)alloc((size_t)MAXB * H_DIM * 2);   // 69.2 MB (h -> hd in-place)
    __hip_bfloat16* Wt1  = (__hip_bfloat16*)alloc((size_t)L_DIM * H_DIM * 2);
    __hip_bfloat16* Wt2  = (__hip_bfloat16*)alloc((size_t)H_DIM * E_DIM * 2);
    __hip_bfloat16* Wd1t = (__hip_bfloat16*)alloc((size_t)K_EXP * E_DIM * H_DIM * 2);
    __hip_bfloat16* Wd2t = (__hip_bfloat16*)alloc((size_t)K_EXP * H_DIM * L_DIM * 2);

    k_ids_hist<<<NBLK, 256, 0, stream>>>(x, ids, hist);
    k_scan<<<1, 64, 0, stream>>>(hist, base, meta, order_pad);
    k_order<<<NBLK, 256, 0, stream>>>(ids, base, order_pad);
    k_gather<<<(MAXB * (L_DIM / 4)) / 256, 256, 0, stream>>>(x, order_pad, xs);
    k_wtrans<<<5760, 256, 0, stream>>>(We1, We2, Wd1, Wd2, Wt1, Wt2, Wd1t, Wd2t);

    // G1: h = leaky(xs @ We1 + be1)   [MAXB,512]@[512,1024]
    gemm_g1<<<MAXT * (H_DIM / 128), 256, 0, stream>>>(xs, Wt1, be1, hbuf);
    // G23: hd = leaky(leaky(h @ We2 + be2) @ Wd1[e] + bd1[e])   (z stays in LDS)
    gemm_g23<<<MAXB / 64, 256, 0, stream>>>(hbuf, Wt2, be2, Wd1t, bd1, hbuf, meta);
    // G4: out = hd @ Wd2[e] + bd2[e]  (padded -> output rows)
    gemm_g4<<<MAXT * (L_DIM / 128), 256, 0, stream>>>(hbuf, Wd2t, bd2, out, meta);
}

// Round 10
// 204.839 us; speedup vs baseline: 1.0169x; 1.0169x over previous
//
#include <hip/hip_runtime.h>
#include <hip/hip_bf16.h>

#define B_ROWS 32768
#define L_DIM 512
#define H_DIM 1024
#define E_DIM 128
#define K_EXP 8
#define NBLK 128   // sort blocks: 32768/256

typedef __bf16 bf16x8 __attribute__((ext_vector_type(8)));
typedef float f32x4 __attribute__((ext_vector_type(4)));

__device__ __forceinline__ void gload16(const void* src, void* dst) {
    __builtin_amdgcn_global_load_lds(
        (const __attribute__((address_space(1))) unsigned int*)src,
        (__attribute__((address_space(3))) unsigned int*)dst, 16, 0, 0);
}

// ---------------- sort: ids + per-block histogram ----------------
__global__ void k_ids_hist(const float* __restrict__ x, int* __restrict__ ids,
                           int* __restrict__ hist) {
    __shared__ int lh[K_EXP];
    int t = threadIdx.x;
    if (t < K_EXP) lh[t] = 0;
    __syncthreads();
    int i = blockIdx.x * 256 + t;
    int id = (int)x[(size_t)i * (L_DIM + 1) + L_DIM];
    ids[i] = id;
    atomicAdd(&lh[id], 1);
    __syncthreads();
    if (t < K_EXP) hist[blockIdx.x * K_EXP + t] = lh[t];
}

__global__ void k_scan(const int* __restrict__ hist, int* __restrict__ base,
                       int* __restrict__ seg, int* __restrict__ tp) {
    __shared__ int c[K_EXP];
    __shared__ int sseg[K_EXP + 1];
    int k = threadIdx.x;
    if (k < K_EXP) {
        int run = 0;
        for (int b = 0; b < NBLK; ++b) {
            base[b * K_EXP + k] = run;
            run += hist[b * K_EXP + k];
        }
        c[k] = run;
    }
    __syncthreads();
    if (k == 0) {
        int s = 0, t2 = 0;
        for (int e = 0; e < K_EXP; ++e) {
            sseg[e] = s; seg[e] = s; tp[e] = t2;
            s += c[e]; t2 += (c[e] + 127) >> 7;
        }
        sseg[K_EXP] = s; seg[K_EXP] = s; tp[K_EXP] = t2;
    }
    __syncthreads();
    if (k < K_EXP) {
        int s0 = sseg[k];
        for (int b = 0; b < NBLK; ++b) base[b * K_EXP + k] += s0;
    }
}

__global__ void k_order(const int* __restrict__ ids, const int* __restrict__ base,
                        int* __restrict__ order) {
    __shared__ int sid[256];
    int t = threadIdx.x;
    int i = blockIdx.x * 256 + t;
    int my = ids[i];
    sid[t] = my;
    __syncthreads();
    int rank = 0;
    for (int j = 0; j < t; ++j) rank += (sid[j] == my) ? 1 : 0;
    order[base[blockIdx.x * K_EXP + my] + rank] = i;
}

// 8 floats/thread: two float4 loads from the (row-scattered) source, one 16B store
__global__ void k_gather(const float* __restrict__ x, const int* __restrict__ order,
                         __hip_bfloat16* __restrict__ xs) {
    int idx = blockIdx.x * 256 + threadIdx.x;
    int p = idx >> 6;                 // 64 groups of 8 per row
    int c8 = (idx & 63) << 3;
    int src = order[p];
    const float* sp = x + (size_t)src * (L_DIM + 1) + c8;
    float4 a = *(const float4*)(sp);
    float4 b = *(const float4*)(sp + 4);
    __hip_bfloat16 v[8];
    v[0] = __float2bfloat16(a.x); v[1] = __float2bfloat16(a.y);
    v[2] = __float2bfloat16(a.z); v[3] = __float2bfloat16(a.w);
    v[4] = __float2bfloat16(b.x); v[5] = __float2bfloat16(b.y);
    v[6] = __float2bfloat16(b.z); v[7] = __float2bfloat16(b.w);
    *(uint4*)(xs + (size_t)p * L_DIM + c8) = *(uint4*)v;
}

// ---------------- fused weight transpose + fp32->bf16 (all 4 weights, 1 launch) ----------------
__global__ void k_wtrans(const float* __restrict__ We1, const float* __restrict__ We2,
                         const float* __restrict__ Wd1, const float* __restrict__ Wd2,
                         __hip_bfloat16* __restrict__ Wt1, __hip_bfloat16* __restrict__ Wt2,
                         __hip_bfloat16* __restrict__ Wd1t, __hip_bfloat16* __restrict__ Wd2t) {
    __shared__ float tile[32][33];
    int b = blockIdx.x;
    const float* W;
    __hip_bfloat16* Wt;
    int KDim, NDim, local;
    if (b < 512)       { W = We1; Wt = Wt1; KDim = 512;  NDim = 1024; local = b; }
    else if (b < 640)  { W = We2; Wt = Wt2; KDim = 1024; NDim = 128;  local = b - 512; }
    else if (b < 1664) {
        int lb = b - 640;
        int e = lb >> 7;
        local = lb & 127;
        KDim = 128; NDim = 1024;
        W = Wd1 + (size_t)e * KDim * NDim;
        Wt = Wd1t + (size_t)e * KDim * NDim;
    } else {
        int lb = b - 1664;
        int e = lb >> 9;
        local = lb & 511;
        KDim = 1024; NDim = 512;
        W = Wd2 + (size_t)e * KDim * NDim;
        Wt = Wd2t + (size_t)e * KDim * NDim;
    }
    int ntK = KDim >> 5;
    int k0 = (local % ntK) << 5, n0 = (local / ntK) << 5;
    int tx = threadIdx.x & 31, ty = threadIdx.x >> 5;
    for (int i = ty; i < 32; i += 8)
        tile[i][tx] = W[(size_t)(k0 + i) * NDim + n0 + tx];
    __syncthreads();
    for (int i = ty; i < 32; i += 8)
        Wt[(size_t)(n0 + i) * KDim + k0 + tx] = __float2bfloat16(tile[tx][i]);
}

// ---------------- ring-3 MFMA GEMM body (R5/R8-proven) ----------------
template <int BM, int KD, int ND, bool GROUPED, bool LEAKY, bool OUT_BF16>
__device__ __forceinline__ void gemm_body(__hip_bfloat16* smem,
                                          const __hip_bfloat16* __restrict__ A,
                                          const __hip_bfloat16* __restrict__ Bt,
                                          const float* __restrict__ bias,
                                          void* __restrict__ Cout,
                                          const int* __restrict__ seg,
                                          const int* __restrict__ tp) {
    constexpr int NNT = ND / 128;
    constexpr int NMT = GROUPED ? (B_ROWS / 128 + K_EXP) : (B_ROWS / BM);
    constexpr int TOT = NMT * NNT;
    static_assert(TOT % 8 == 0, "XCD chunking needs TOT % 8 == 0");
    constexpr int ACH = BM * 32;
    constexpr int SLOT = ACH + 128 * 32;
    constexpr int NK = KD / 32;
    constexpr int VG = (BM == 128) ? 4 : 3;

    const int id = blockIdx.x;
    const int wg = (id & 7) * (TOT / 8) + (id >> 3);
    const int mt = wg / NNT, nt = wg % NNT;
    const int n0 = nt << 7;
    int m0, mEnd;
    const __hip_bfloat16* Bp = Bt;
    const float* bp = bias;
    if (GROUPED) {
        if (mt >= tp[K_EXP]) return;
        int e = 0;
        while (mt >= tp[e + 1]) ++e;
        m0 = seg[e] + ((mt - tp[e]) << 7);
        mEnd = seg[e + 1];
        Bp += (size_t)e * KD * ND;
        bp += (size_t)e * ND;
    } else {
        m0 = mt * BM;
        mEnd = m0 + BM;
    }
    const int t = threadIdx.x, w = t >> 6, l = t & 63;
    constexpr int FM = BM / 32;
    const int wm = w >> 1, wn = w & 1, g = l >> 4, li = l & 15;
    const int r0 = l >> 2, s0 = l & 3;

    f32x4 acc[FM][4];
#pragma unroll
    for (int i = 0; i < FM; ++i)
#pragma unroll
        for (int j = 0; j < 4; ++j) acc[i][j] = (f32x4){0.f, 0.f, 0.f, 0.f};

    auto stage = [&](int b, int kt) {
#pragma unroll
        for (int qi = 0; qi < BM / 64; ++qi) {
            int q = (BM / 64) * w + qi;
            int r = q * 16 + r0;
            int ksg = s0 ^ ((r >> 1) & 3);
            int rowg = m0 + r;
            if (GROUPED) rowg = min(rowg, B_ROWS - 1);
            gload16(A + (size_t)rowg * KD + kt * 32 + ksg * 8,
                    &smem[b * SLOT + q * 512]);
        }
#pragma unroll
        for (int qi = 0; qi < 2; ++qi) {
            int q = 2 * w + qi;
            int r = q * 16 + r0;
            int ksg = s0 ^ ((r >> 1) & 3);
            gload16(Bp + (size_t)(n0 + r) * KD + kt * 32 + ksg * 8,
                    &smem[b * SLOT + ACH + q * 512]);
        }
    };

    stage(0, 0);
    stage(1, 1);
    int b = 0;
    for (int kt = 0; kt < NK; ++kt) {
        if (kt == NK - 1)
            asm volatile("s_waitcnt vmcnt(0)\ns_barrier" ::: "memory");
        else if constexpr (VG == 4)
            asm volatile("s_waitcnt vmcnt(4)\ns_barrier" ::: "memory");
        else
            asm volatile("s_waitcnt vmcnt(3)\ns_barrier" ::: "memory");
        __builtin_amdgcn_sched_barrier(0);
        if (kt + 2 < NK) stage((b + 2 >= 3) ? b - 1 : b + 2, kt + 2);
        bf16x8 af[FM], bfr[4];
#pragma unroll
        for (int fm = 0; fm < FM; ++fm) {
            int rr = wm * (FM * 16) + fm * 16 + li;
            int ss = g ^ ((rr >> 1) & 3);
            af[fm] = *(const bf16x8*)&smem[b * SLOT + rr * 32 + ss * 8];
        }
#pragma unroll
        for (int fn = 0; fn < 4; ++fn) {
            int cc = wn * 64 + fn * 16 + li;
            int ss = g ^ ((cc >> 1) & 3);
            bfr[fn] = *(const bf16x8*)&smem[b * SLOT + ACH + cc * 32 + ss * 8];
        }
        __builtin_amdgcn_s_setprio(1);
#pragma unroll
        for (int fm = 0; fm < FM; ++fm)
#pragma unroll
            for (int fn = 0; fn < 4; ++fn)
                acc[fm][fn] = __builtin_amdgcn_mfma_f32_16x16x32_bf16(
                    af[fm], bfr[fn], acc[fm][fn], 0, 0, 0);
        __builtin_amdgcn_s_setprio(0);
        b = (b + 1 >= 3) ? 0 : b + 1;
    }

    float bv[4];
#pragma unroll
    for (int fn = 0; fn < 4; ++fn) bv[fn] = bp[n0 + wn * 64 + fn * 16 + li];
#pragma unroll
    for (int fm = 0; fm < FM; ++fm)
#pragma unroll
        for (int i = 0; i < 4; ++i) {
            int r = m0 + wm * (FM * 16) + fm * 16 + g * 4 + i;
            if (!GROUPED || r < mEnd) {
#pragma unroll
                for (int fn = 0; fn < 4; ++fn) {
                    float v = acc[fm][fn][i] + bv[fn];
                    if (LEAKY) v = v > 0.f ? v : 0.01f * v;
                    size_t off = (size_t)r * ND + n0 + wn * 64 + fn * 16 + li;
                    if (OUT_BF16)
                        ((__hip_bfloat16*)Cout)[off] = __float2bfloat16(v);
                    else
                        ((float*)Cout)[off] = v;
                }
            }
        }
}

// ---- named wrappers (distinct rocprof rows) ----
__global__ __launch_bounds__(256) void gemm_g1(const __hip_bfloat16* A, const __hip_bfloat16* Bt,
                                               const float* bias, void* C) {
    __shared__ __align__(16) __hip_bfloat16 smem[3 * (128 * 32 + 128 * 32)];
    gemm_body<128, L_DIM, H_DIM, false, true, true>(smem, A, Bt, bias, C, nullptr, nullptr);
}
__global__ __launch_bounds__(256) void gemm_g2(const __hip_bfloat16* A, const __hip_bfloat16* Bt,
                                               const float* bias, void* C) {
    __shared__ __align__(16) __hip_bfloat16 smem[3 * (64 * 32 + 128 * 32)];
    gemm_body<64, H_DIM, E_DIM, false, true, true>(smem, A, Bt, bias, C, nullptr, nullptr);
}
__global__ __launch_bounds__(256) void gemm_g4(const __hip_bfloat16* A, const __hip_bfloat16* Bt,
                                               const float* bias, void* C,
                                               const int* seg, const int* tp) {
    __shared__ __align__(16) __hip_bfloat16 smem[3 * (128 * 32 + 128 * 32)];
    gemm_body<128, H_DIM, L_DIM, true, false, false>(smem, A, Bt, bias, C, seg, tp);
}

// ---------------- G3: single-shot K=128 grouped GEMM (R8-proven) ----------------
__global__ __launch_bounds__(256) void gemm_g3(const __hip_bfloat16* __restrict__ A,
                                               const __hip_bfloat16* __restrict__ Bt,
                                               const float* __restrict__ bias,
                                               __hip_bfloat16* __restrict__ Cout,
                                               const int* __restrict__ seg,
                                               const int* __restrict__ tp) {
    constexpr int KD = E_DIM;   // 128
    constexpr int ND = H_DIM;   // 1024
    constexpr int NNT = ND / 128;
    constexpr int NMT = B_ROWS / 128 + K_EXP;
    constexpr int TOT = NMT * NNT;   // 2112
    static_assert(TOT % 8 == 0, "XCD chunking");
    constexpr int SLOT = 2 * 128 * 32;
    __shared__ __align__(16) __hip_bfloat16 smem[4 * SLOT];  // 64 KB

    const int id = blockIdx.x;
    const int wg = (id & 7) * (TOT / 8) + (id >> 3);
    const int mt = wg / NNT, nt = wg % NNT;
    const int n0 = nt << 7;
    if (mt >= tp[K_EXP]) return;
    int e = 0;
    while (mt >= tp[e + 1]) ++e;
    const int m0 = seg[e] + ((mt - tp[e]) << 7);
    const int mEnd = seg[e + 1];
    const __hip_bfloat16* Bp = Bt + (size_t)e * KD * ND;
    const float* bp = bias + (size_t)e * ND;

    const int t = threadIdx.x, w = t >> 6, l = t & 63;
    const int wm = w >> 1, wn = w & 1, g = l >> 4, li = l & 15;
    const int q0 = 2 * w, r0 = l >> 2, s0 = l & 3;

#pragma unroll
    for (int kt = 0; kt < 4; ++kt) {
#pragma unroll
        for (int qi = 0; qi < 2; ++qi) {
            int q = q0 + qi, r = q * 16 + r0;
            int ksg = s0 ^ ((r >> 1) & 3);
            int rowg = min(m0 + r, B_ROWS - 1);
            gload16(A + (size_t)rowg * KD + kt * 32 + ksg * 8,
                    &smem[kt * SLOT + q * 512]);
        }
#pragma unroll
        for (int qi = 0; qi < 2; ++qi) {
            int q = q0 + qi, r = q * 16 + r0;
            int ksg = s0 ^ ((r >> 1) & 3);
            gload16(Bp + (size_t)(n0 + r) * KD + kt * 32 + ksg * 8,
                    &smem[kt * SLOT + 4096 + q * 512]);
        }
    }
    asm volatile("s_waitcnt vmcnt(0)\ns_barrier" ::: "memory");

    f32x4 acc[4][4];
#pragma unroll
    for (int i = 0; i < 4; ++i)
#pragma unroll
        for (int j = 0; j < 4; ++j) acc[i][j] = (f32x4){0.f, 0.f, 0.f, 0.f};

#pragma unroll
    for (int kt = 0; kt < 4; ++kt) {
        bf16x8 af[4], bfr[4];
#pragma unroll
        for (int fm = 0; fm < 4; ++fm) {
            int rr = wm * 64 + fm * 16 + li;
            int ss = g ^ ((rr >> 1) & 3);
            af[fm] = *(const bf16x8*)&smem[kt * SLOT + rr * 32 + ss * 8];
        }
#pragma unroll
        for (int fn = 0; fn < 4; ++fn) {
            int cc = wn * 64 + fn * 16 + li;
            int ss = g ^ ((cc >> 1) & 3);
            bfr[fn] = *(const bf16x8*)&smem[kt * SLOT + 4096 + cc * 32 + ss * 8];
        }
        __builtin_amdgcn_s_setprio(1);
#pragma unroll
        for (int fm = 0; fm < 4; ++fm)
#pragma unroll
            for (int fn = 0; fn < 4; ++fn)
                acc[fm][fn] = __builtin_amdgcn_mfma_f32_16x16x32_bf16(
                    af[fm], bfr[fn], acc[fm][fn], 0, 0, 0);
        __builtin_amdgcn_s_setprio(0);
    }

    float bv[4];
#pragma unroll
    for (int fn = 0; fn < 4; ++fn) bv[fn] = bp[n0 + wn * 64 + fn * 16 + li];
#pragma unroll
    for (int fm = 0; fm < 4; ++fm)
#pragma unroll
        for (int i = 0; i < 4; ++i) {
            int r = m0 + wm * 64 + fm * 16 + g * 4 + i;
            if (r < mEnd) {
#pragma unroll
                for (int fn = 0; fn < 4; ++fn) {
                    float v = acc[fm][fn][i] + bv[fn];
                    v = v > 0.f ? v : 0.01f * v;
                    Cout[(size_t)r * ND + n0 + wn * 64 + fn * 16 + li] = __float2bfloat16(v);
                }
            }
        }
}

extern "C" void kernel_launch(void* const* d_in, const int* in_sizes, int n_in,
                              void* d_out, int out_size, void* d_ws, size_t ws_size,
                              hipStream_t stream) {
    (void)in_sizes; (void)n_in; (void)out_size; (void)ws_size;
    const float* x   = (const float*)d_in[0];
    const float* We1 = (const float*)d_in[1];
    const float* be1 = (const float*)d_in[2];
    const float* We2 = (const float*)d_in[3];
    const float* be2 = (const float*)d_in[4];
    const float* Wd1 = (const float*)d_in[5];
    const float* bd1 = (const float*)d_in[6];
    const float* Wd2 = (const float*)d_in[7];
    const float* bd2 = (const float*)d_in[8];
    float* out = (float*)d_out;

    char* w = (char*)d_ws;
    auto alloc = [&](size_t bytes) {
        char* p = w;
        w += (bytes + 255) & ~(size_t)255;
        return p;
    };
    int* ids   = (int*)alloc((size_t)B_ROWS * 4);
    int* order = (int*)alloc((size_t)B_ROWS * 4);
    int* hist  = (int*)alloc((size_t)NBLK * K_EXP * 4);
    int* base  = (int*)alloc((size_t)NBLK * K_EXP * 4);
    int* seg   = (int*)alloc((K_EXP + 1) * 4);
    int* tp    = (int*)alloc((K_EXP + 1) * 4);
    __hip_bfloat16* xs   = (__hip_bfloat16*)alloc((size_t)B_ROWS * L_DIM * 2);
    __hip_bfloat16* hbuf = (__hip_bfloat16*)alloc((size_t)B_ROWS * H_DIM * 2);
    __hip_bfloat16* zbuf = (__hip_bfloat16*)alloc((size_t)B_ROWS * E_DIM * 2);
    __hip_bfloat16* Wt1  = (__hip_bfloat16*)alloc((size_t)L_DIM * H_DIM * 2);
    __hip_bfloat16* Wt2  = (__hip_bfloat16*)alloc((size_t)H_DIM * E_DIM * 2);
    __hip_bfloat16* Wd1t = (__hip_bfloat16*)alloc((size_t)K_EXP * E_DIM * H_DIM * 2);
    __hip_bfloat16* Wd2t = (__hip_bfloat16*)alloc((size_t)K_EXP * H_DIM * L_DIM * 2);

    k_ids_hist<<<NBLK, 256, 0, stream>>>(x, ids, hist);
    k_scan<<<1, 64, 0, stream>>>(hist, base, seg, tp);
    k_order<<<NBLK, 256, 0, stream>>>(ids, base, order);
    k_gather<<<(B_ROWS * (L_DIM / 8)) / 256, 256, 0, stream>>>(x, order, xs);
    k_wtrans<<<5760, 256, 0, stream>>>(We1, We2, Wd1, Wd2, Wt1, Wt2, Wd1t, Wd2t);

    // G1: h = leaky(xs @ We1 + be1)      [32768,512]@[512,1024]
    gemm_g1<<<(B_ROWS / 128) * (H_DIM / 128), 256, 0, stream>>>(xs, Wt1, be1, hbuf);
    // G2: z = leaky(h @ We2 + be2)       [32768,1024]@[1024,128]
    gemm_g2<<<(B_ROWS / 64) * (E_DIM / 128), 256, 0, stream>>>(hbuf, Wt2, be2, zbuf);
    // G3: hd = leaky(z @ Wd1[e] + bd1[e])  grouped, single-shot K=128
    gemm_g3<<<(B_ROWS / 128 + K_EXP) * (H_DIM / 128), 256, 0, stream>>>(zbuf, Wd1t, bd1, hbuf, seg, tp);
    // G4: out = hd @ Wd2[e] + bd2[e]     grouped, fp32 out
    gemm_g4<<<(B_ROWS / 128 + K_EXP) * (L_DIM / 128), 256, 0, stream>>>(hbuf, Wd2t, bd2, out, seg, tp);
}

// Round 11
// 195.627 us; speedup vs baseline: 1.0648x; 1.0471x over previous
//
#include <hip/hip_runtime.h>
#include <hip/hip_bf16.h>

#define B_ROWS 32768
#define L_DIM 512
#define H_DIM 1024
#define E_DIM 128
#define K_EXP 8
#define NBLK 128   // sort blocks: 32768/256

typedef __bf16 bf16x8 __attribute__((ext_vector_type(8)));
typedef float f32x4 __attribute__((ext_vector_type(4)));

__device__ __forceinline__ void gload16(const void* src, void* dst) {
    __builtin_amdgcn_global_load_lds(
        (const __attribute__((address_space(1))) unsigned int*)src,
        (__attribute__((address_space(3))) unsigned int*)dst, 16, 0, 0);
}

// ---------------- fused prepass: ids+histogram (blocks 0..127) ∥ weight transpose ----------------
__global__ void k_pre(const float* __restrict__ x, int* __restrict__ ids,
                      int* __restrict__ hist,
                      const float* __restrict__ We1, const float* __restrict__ We2,
                      const float* __restrict__ Wd1, const float* __restrict__ Wd2,
                      __hip_bfloat16* __restrict__ Wt1, __hip_bfloat16* __restrict__ Wt2,
                      __hip_bfloat16* __restrict__ Wd1t, __hip_bfloat16* __restrict__ Wd2t) {
    __shared__ float tile[32][33];
    __shared__ int lh[K_EXP];
    int b = blockIdx.x;
    int t = threadIdx.x;
    if (b < NBLK) {
        // ids + per-block histogram
        if (t < K_EXP) lh[t] = 0;
        __syncthreads();
        int i = b * 256 + t;
        int id = (int)x[(size_t)i * (L_DIM + 1) + L_DIM];
        ids[i] = id;
        atomicAdd(&lh[id], 1);
        __syncthreads();
        if (t < K_EXP) hist[b * K_EXP + t] = lh[t];
        return;
    }
    // weight transpose + fp32->bf16
    b -= NBLK;
    const float* W;
    __hip_bfloat16* Wt;
    int KDim, NDim, local;
    if (b < 512)       { W = We1; Wt = Wt1; KDim = 512;  NDim = 1024; local = b; }
    else if (b < 640)  { W = We2; Wt = Wt2; KDim = 1024; NDim = 128;  local = b - 512; }
    else if (b < 1664) {
        int lb = b - 640;
        int e = lb >> 7;
        local = lb & 127;
        KDim = 128; NDim = 1024;
        W = Wd1 + (size_t)e * KDim * NDim;
        Wt = Wd1t + (size_t)e * KDim * NDim;
    } else {
        int lb = b - 1664;
        int e = lb >> 9;
        local = lb & 511;
        KDim = 1024; NDim = 512;
        W = Wd2 + (size_t)e * KDim * NDim;
        Wt = Wd2t + (size_t)e * KDim * NDim;
    }
    int ntK = KDim >> 5;
    int k0 = (local % ntK) << 5, n0 = (local / ntK) << 5;
    int tx = t & 31, ty = t >> 5;
    for (int i = ty; i < 32; i += 8)
        tile[i][tx] = W[(size_t)(k0 + i) * NDim + n0 + tx];
    __syncthreads();
    for (int i = ty; i < 32; i += 8)
        Wt[(size_t)(n0 + i) * KDim + k0 + tx] = __float2bfloat16(tile[tx][i]);
}

__global__ void k_scan(const int* __restrict__ hist, int* __restrict__ base,
                       int* __restrict__ seg, int* __restrict__ tp) {
    __shared__ int c[K_EXP];
    __shared__ int sseg[K_EXP + 1];
    int k = threadIdx.x;
    if (k < K_EXP) {
        int run = 0;
        for (int b = 0; b < NBLK; ++b) {
            base[b * K_EXP + k] = run;
            run += hist[b * K_EXP + k];
        }
        c[k] = run;
    }
    __syncthreads();
    if (k == 0) {
        int s = 0, t2 = 0;
        for (int e = 0; e < K_EXP; ++e) {
            sseg[e] = s; seg[e] = s; tp[e] = t2;
            s += c[e]; t2 += (c[e] + 127) >> 7;
        }
        sseg[K_EXP] = s; seg[K_EXP] = s; tp[K_EXP] = t2;
    }
    __syncthreads();
    if (k < K_EXP) {
        int s0 = sseg[k];
        for (int b = 0; b < NBLK; ++b) base[b * K_EXP + k] += s0;
    }
}

__global__ void k_order(const int* __restrict__ ids, const int* __restrict__ base,
                        int* __restrict__ order) {
    __shared__ int sid[256];
    int t = threadIdx.x;
    int i = blockIdx.x * 256 + t;
    int my = ids[i];
    sid[t] = my;
    __syncthreads();
    int rank = 0;
    for (int j = 0; j < t; ++j) rank += (sid[j] == my) ? 1 : 0;
    order[base[blockIdx.x * K_EXP + my] + rank] = i;
}

// 8 floats/thread: two float4 loads from the (row-scattered) source, one 16B store
__global__ void k_gather(const float* __restrict__ x, const int* __restrict__ order,
                         __hip_bfloat16* __restrict__ xs) {
    int idx = blockIdx.x * 256 + threadIdx.x;
    int p = idx >> 6;                 // 64 groups of 8 per row
    int c8 = (idx & 63) << 3;
    int src = order[p];
    const float* sp = x + (size_t)src * (L_DIM + 1) + c8;
    float4 a = *(const float4*)(sp);
    float4 b = *(const float4*)(sp + 4);
    __hip_bfloat16 v[8];
    v[0] = __float2bfloat16(a.x); v[1] = __float2bfloat16(a.y);
    v[2] = __float2bfloat16(a.z); v[3] = __float2bfloat16(a.w);
    v[4] = __float2bfloat16(b.x); v[5] = __float2bfloat16(b.y);
    v[6] = __float2bfloat16(b.z); v[7] = __float2bfloat16(b.w);
    *(uint4*)(xs + (size_t)p * L_DIM + c8) = *(uint4*)v;
}

// ---------------- ring-3 MFMA GEMM body (R5/R8-proven) ----------------
template <int BM, int KD, int ND, bool GROUPED, bool LEAKY, bool OUT_BF16>
__device__ __forceinline__ void gemm_body(__hip_bfloat16* smem,
                                          const __hip_bfloat16* __restrict__ A,
                                          const __hip_bfloat16* __restrict__ Bt,
                                          const float* __restrict__ bias,
                                          void* __restrict__ Cout,
                                          const int* __restrict__ seg,
                                          const int* __restrict__ tp) {
    constexpr int NNT = ND / 128;
    constexpr int NMT = GROUPED ? (B_ROWS / 128 + K_EXP) : (B_ROWS / BM);
    constexpr int TOT = NMT * NNT;
    static_assert(TOT % 8 == 0, "XCD chunking needs TOT % 8 == 0");
    constexpr int ACH = BM * 32;
    constexpr int SLOT = ACH + 128 * 32;
    constexpr int NK = KD / 32;
    constexpr int VG = (BM == 128) ? 4 : 3;

    const int id = blockIdx.x;
    const int wg = (id & 7) * (TOT / 8) + (id >> 3);
    const int mt = wg / NNT, nt = wg % NNT;
    const int n0 = nt << 7;
    int m0, mEnd;
    const __hip_bfloat16* Bp = Bt;
    const float* bp = bias;
    if (GROUPED) {
        if (mt >= tp[K_EXP]) return;
        int e = 0;
        while (mt >= tp[e + 1]) ++e;
        m0 = seg[e] + ((mt - tp[e]) << 7);
        mEnd = seg[e + 1];
        Bp += (size_t)e * KD * ND;
        bp += (size_t)e * ND;
    } else {
        m0 = mt * BM;
        mEnd = m0 + BM;
    }
    const int t = threadIdx.x, w = t >> 6, l = t & 63;
    constexpr int FM = BM / 32;
    const int wm = w >> 1, wn = w & 1, g = l >> 4, li = l & 15;
    const int r0 = l >> 2, s0 = l & 3;

    f32x4 acc[FM][4];
#pragma unroll
    for (int i = 0; i < FM; ++i)
#pragma unroll
        for (int j = 0; j < 4; ++j) acc[i][j] = (f32x4){0.f, 0.f, 0.f, 0.f};

    auto stage = [&](int b, int kt) {
#pragma unroll
        for (int qi = 0; qi < BM / 64; ++qi) {
            int q = (BM / 64) * w + qi;
            int r = q * 16 + r0;
            int ksg = s0 ^ ((r >> 1) & 3);
            int rowg = m0 + r;
            if (GROUPED) rowg = min(rowg, B_ROWS - 1);
            gload16(A + (size_t)rowg * KD + kt * 32 + ksg * 8,
                    &smem[b * SLOT + q * 512]);
        }
#pragma unroll
        for (int qi = 0; qi < 2; ++qi) {
            int q = 2 * w + qi;
            int r = q * 16 + r0;
            int ksg = s0 ^ ((r >> 1) & 3);
            gload16(Bp + (size_t)(n0 + r) * KD + kt * 32 + ksg * 8,
                    &smem[b * SLOT + ACH + q * 512]);
        }
    };

    stage(0, 0);
    stage(1, 1);
    int b = 0;
    for (int kt = 0; kt < NK; ++kt) {
        if (kt == NK - 1)
            asm volatile("s_waitcnt vmcnt(0)\ns_barrier" ::: "memory");
        else if constexpr (VG == 4)
            asm volatile("s_waitcnt vmcnt(4)\ns_barrier" ::: "memory");
        else
            asm volatile("s_waitcnt vmcnt(3)\ns_barrier" ::: "memory");
        __builtin_amdgcn_sched_barrier(0);
        if (kt + 2 < NK) stage((b + 2 >= 3) ? b - 1 : b + 2, kt + 2);
        bf16x8 af[FM], bfr[4];
#pragma unroll
        for (int fm = 0; fm < FM; ++fm) {
            int rr = wm * (FM * 16) + fm * 16 + li;
            int ss = g ^ ((rr >> 1) & 3);
            af[fm] = *(const bf16x8*)&smem[b * SLOT + rr * 32 + ss * 8];
        }
#pragma unroll
        for (int fn = 0; fn < 4; ++fn) {
            int cc = wn * 64 + fn * 16 + li;
            int ss = g ^ ((cc >> 1) & 3);
            bfr[fn] = *(const bf16x8*)&smem[b * SLOT + ACH + cc * 32 + ss * 8];
        }
        __builtin_amdgcn_s_setprio(1);
#pragma unroll
        for (int fm = 0; fm < FM; ++fm)
#pragma unroll
            for (int fn = 0; fn < 4; ++fn)
                acc[fm][fn] = __builtin_amdgcn_mfma_f32_16x16x32_bf16(
                    af[fm], bfr[fn], acc[fm][fn], 0, 0, 0);
        __builtin_amdgcn_s_setprio(0);
        b = (b + 1 >= 3) ? 0 : b + 1;
    }

    float bv[4];
#pragma unroll
    for (int fn = 0; fn < 4; ++fn) bv[fn] = bp[n0 + wn * 64 + fn * 16 + li];
#pragma unroll
    for (int fm = 0; fm < FM; ++fm)
#pragma unroll
        for (int i = 0; i < 4; ++i) {
            int r = m0 + wm * (FM * 16) + fm * 16 + g * 4 + i;
            if (!GROUPED || r < mEnd) {
#pragma unroll
                for (int fn = 0; fn < 4; ++fn) {
                    float v = acc[fm][fn][i] + bv[fn];
                    if (LEAKY) v = v > 0.f ? v : 0.01f * v;
                    size_t off = (size_t)r * ND + n0 + wn * 64 + fn * 16 + li;
                    if (OUT_BF16)
                        ((__hip_bfloat16*)Cout)[off] = __float2bfloat16(v);
                    else
                        ((float*)Cout)[off] = v;
                }
            }
        }
}

// ---- named wrappers (distinct rocprof rows) ----
__global__ __launch_bounds__(256) void gemm_g1(const __hip_bfloat16* A, const __hip_bfloat16* Bt,
                                               const float* bias, void* C) {
    __shared__ __align__(16) __hip_bfloat16 smem[3 * (128 * 32 + 128 * 32)];
    gemm_body<128, L_DIM, H_DIM, false, true, true>(smem, A, Bt, bias, C, nullptr, nullptr);
}
__global__ __launch_bounds__(256) void gemm_g2(const __hip_bfloat16* A, const __hip_bfloat16* Bt,
                                               const float* bias, void* C) {
    __shared__ __align__(16) __hip_bfloat16 smem[3 * (64 * 32 + 128 * 32)];
    gemm_body<64, H_DIM, E_DIM, false, true, true>(smem, A, Bt, bias, C, nullptr, nullptr);
}
__global__ __launch_bounds__(256) void gemm_g4(const __hip_bfloat16* A, const __hip_bfloat16* Bt,
                                               const float* bias, void* C,
                                               const int* seg, const int* tp) {
    __shared__ __align__(16) __hip_bfloat16 smem[3 * (128 * 32 + 128 * 32)];
    gemm_body<128, H_DIM, L_DIM, true, false, false>(smem, A, Bt, bias, C, seg, tp);
}

// ---------------- G3: single-shot K=128 grouped GEMM (R8-proven) ----------------
__global__ __launch_bounds__(256) void gemm_g3(const __hip_bfloat16* __restrict__ A,
                                               const __hip_bfloat16* __restrict__ Bt,
                                               const float* __restrict__ bias,
                                               __hip_bfloat16* __restrict__ Cout,
                                               const int* __restrict__ seg,
                                               const int* __restrict__ tp) {
    constexpr int KD = E_DIM;   // 128
    constexpr int ND = H_DIM;   // 1024
    constexpr int NNT = ND / 128;
    constexpr int NMT = B_ROWS / 128 + K_EXP;
    constexpr int TOT = NMT * NNT;   // 2112
    static_assert(TOT % 8 == 0, "XCD chunking");
    constexpr int SLOT = 2 * 128 * 32;
    __shared__ __align__(16) __hip_bfloat16 smem[4 * SLOT];  // 64 KB

    const int id = blockIdx.x;
    const int wg = (id & 7) * (TOT / 8) + (id >> 3);
    const int mt = wg / NNT, nt = wg % NNT;
    const int n0 = nt << 7;
    if (mt >= tp[K_EXP]) return;
    int e = 0;
    while (mt >= tp[e + 1]) ++e;
    const int m0 = seg[e] + ((mt - tp[e]) << 7);
    const int mEnd = seg[e + 1];
    const __hip_bfloat16* Bp = Bt + (size_t)e * KD * ND;
    const float* bp = bias + (size_t)e * ND;

    const int t = threadIdx.x, w = t >> 6, l = t & 63;
    const int wm = w >> 1, wn = w & 1, g = l >> 4, li = l & 15;
    const int q0 = 2 * w, r0 = l >> 2, s0 = l & 3;

#pragma unroll
    for (int kt = 0; kt < 4; ++kt) {
#pragma unroll
        for (int qi = 0; qi < 2; ++qi) {
            int q = q0 + qi, r = q * 16 + r0;
            int ksg = s0 ^ ((r >> 1) & 3);
            int rowg = min(m0 + r, B_ROWS - 1);
            gload16(A + (size_t)rowg * KD + kt * 32 + ksg * 8,
                    &smem[kt * SLOT + q * 512]);
        }
#pragma unroll
        for (int qi = 0; qi < 2; ++qi) {
            int q = q0 + qi, r = q * 16 + r0;
            int ksg = s0 ^ ((r >> 1) & 3);
            gload16(Bp + (size_t)(n0 + r) * KD + kt * 32 + ksg * 8,
                    &smem[kt * SLOT + 4096 + q * 512]);
        }
    }
    asm volatile("s_waitcnt vmcnt(0)\ns_barrier" ::: "memory");

    f32x4 acc[4][4];
#pragma unroll
    for (int i = 0; i < 4; ++i)
#pragma unroll
        for (int j = 0; j < 4; ++j) acc[i][j] = (f32x4){0.f, 0.f, 0.f, 0.f};

#pragma unroll
    for (int kt = 0; kt < 4; ++kt) {
        bf16x8 af[4], bfr[4];
#pragma unroll
        for (int fm = 0; fm < 4; ++fm) {
            int rr = wm * 64 + fm * 16 + li;
            int ss = g ^ ((rr >> 1) & 3);
            af[fm] = *(const bf16x8*)&smem[kt * SLOT + rr * 32 + ss * 8];
        }
#pragma unroll
        for (int fn = 0; fn < 4; ++fn) {
            int cc = wn * 64 + fn * 16 + li;
            int ss = g ^ ((cc >> 1) & 3);
            bfr[fn] = *(const bf16x8*)&smem[kt * SLOT + 4096 + cc * 32 + ss * 8];
        }
        __builtin_amdgcn_s_setprio(1);
#pragma unroll
        for (int fm = 0; fm < 4; ++fm)
#pragma unroll
            for (int fn = 0; fn < 4; ++fn)
                acc[fm][fn] = __builtin_amdgcn_mfma_f32_16x16x32_bf16(
                    af[fm], bfr[fn], acc[fm][fn], 0, 0, 0);
        __builtin_amdgcn_s_setprio(0);
    }

    float bv[4];
#pragma unroll
    for (int fn = 0; fn < 4; ++fn) bv[fn] = bp[n0 + wn * 64 + fn * 16 + li];
#pragma unroll
    for (int fm = 0; fm < 4; ++fm)
#pragma unroll
        for (int i = 0; i < 4; ++i) {
            int r = m0 + wm * 64 + fm * 16 + g * 4 + i;
            if (r < mEnd) {
#pragma unroll
                for (int fn = 0; fn < 4; ++fn) {
                    float v = acc[fm][fn][i] + bv[fn];
                    v = v > 0.f ? v : 0.01f * v;
                    Cout[(size_t)r * ND + n0 + wn * 64 + fn * 16 + li] = __float2bfloat16(v);
                }
            }
        }
}

extern "C" void kernel_launch(void* const* d_in, const int* in_sizes, int n_in,
                              void* d_out, int out_size, void* d_ws, size_t ws_size,
                              hipStream_t stream) {
    (void)in_sizes; (void)n_in; (void)out_size; (void)ws_size;
    const float* x   = (const float*)d_in[0];
    const float* We1 = (const float*)d_in[1];
    const float* be1 = (const float*)d_in[2];
    const float* We2 = (const float*)d_in[3];
    const float* be2 = (const float*)d_in[4];
    const float* Wd1 = (const float*)d_in[5];
    const float* bd1 = (const float*)d_in[6];
    const float* Wd2 = (const float*)d_in[7];
    const float* bd2 = (const float*)d_in[8];
    float* out = (float*)d_out;

    char* w = (char*)d_ws;
    auto alloc = [&](size_t bytes) {
        char* p = w;
        w += (bytes + 255) & ~(size_t)255;
        return p;
    };
    int* ids   = (int*)alloc((size_t)B_ROWS * 4);
    int* order = (int*)alloc((size_t)B_ROWS * 4);
    int* hist  = (int*)alloc((size_t)NBLK * K_EXP * 4);
    int* base  = (int*)alloc((size_t)NBLK * K_EXP * 4);
    int* seg   = (int*)alloc((K_EXP + 1) * 4);
    int* tp    = (int*)alloc((K_EXP + 1) * 4);
    __hip_bfloat16* xs   = (__hip_bfloat16*)alloc((size_t)B_ROWS * L_DIM * 2);
    __hip_bfloat16* hbuf = (__hip_bfloat16*)alloc((size_t)B_ROWS * H_DIM * 2);
    __hip_bfloat16* zbuf = (__hip_bfloat16*)alloc((size_t)B_ROWS * E_DIM * 2);
    __hip_bfloat16* Wt1  = (__hip_bfloat16*)alloc((size_t)L_DIM * H_DIM * 2);
    __hip_bfloat16* Wt2  = (__hip_bfloat16*)alloc((size_t)H_DIM * E_DIM * 2);
    __hip_bfloat16* Wd1t = (__hip_bfloat16*)alloc((size_t)K_EXP * E_DIM * H_DIM * 2);
    __hip_bfloat16* Wd2t = (__hip_bfloat16*)alloc((size_t)K_EXP * H_DIM * L_DIM * 2);

    // prepass: ids+hist (128 blocks) fused with weight transpose (5760 blocks)
    k_pre<<<NBLK + 5760, 256, 0, stream>>>(x, ids, hist, We1, We2, Wd1, Wd2,
                                           Wt1, Wt2, Wd1t, Wd2t);
    k_scan<<<1, 64, 0, stream>>>(hist, base, seg, tp);
    k_order<<<NBLK, 256, 0, stream>>>(ids, base, order);
    k_gather<<<(B_ROWS * (L_DIM / 8)) / 256, 256, 0, stream>>>(x, order, xs);

    // G1: h = leaky(xs @ We1 + be1)      [32768,512]@[512,1024]
    gemm_g1<<<(B_ROWS / 128) * (H_DIM / 128), 256, 0, stream>>>(xs, Wt1, be1, hbuf);
    // G2: z = leaky(h @ We2 + be2)       [32768,1024]@[1024,128]
    gemm_g2<<<(B_ROWS / 64) * (E_DIM / 128), 256, 0, stream>>>(hbuf, Wt2, be2, zbuf);
    // G3: hd = leaky(z @ Wd1[e] + bd1[e])  grouped, single-shot K=128
    gemm_g3<<<(B_ROWS / 128 + K_EXP) * (H_DIM / 128), 256, 0, stream>>>(zbuf, Wd1t, bd1, hbuf, seg, tp);
    // G4: out = hd @ Wd2[e] + bd2[e]     grouped, fp32 out
    gemm_g4<<<(B_ROWS / 128 + K_EXP) * (L_DIM / 128), 256, 0, stream>>>(hbuf, Wd2t, bd2, out, seg, tp);
}